// Round 16
// baseline (252.875 us; speedup 1.0000x reference)
//
#include <hip/hip_runtime.h>
#include <math.h>

#define B5 5
#define DX 4096
#define DT 4096
#define DR 4097   // T + D

// ---------------- workspace layout (floats) ----------------
enum {
  WS_SUMS  = 0,                    // [kld1, kld2, nll]
  WS_CNT_XI  = 3,
  WS_CNT_FIN = 4,
  WS_CNT_ARD = 5,
  WS_ZERO_END = 8,
  WS_ACT1  = 16,                   // relu(h1+b1)   (20480)
  WS_ACT23 = WS_ACT1  + 20480,
  WS_ACT3  = WS_ACT23 + 20480,
  WS_QXI_F = WS_ACT3  + 20480,
  WS_LQC_F = WS_QXI_F + 20480,
  WS_XIV   = WS_LQC_F + 20480,
  WS_Z     = WS_XIV   + 20480,
  WS_KSS   = WS_Z     + 20480,     // 25 (pad 32)
  WS_KXS   = WS_KSS + 32,
  WS_F     = WS_KXS + 32,
  WS_QFM   = WS_F   + 8,
  WS_QFC   = WS_QFM + 8,
  WS_PART  = 143472,               // 16-aligned
  // partials [ks][b][dout], NS=64 (H23: 128)
  WS_P_H1  = WS_PART,
  WS_P_QXI = WS_P_H1  + 1310720,
  WS_P_LQC = WS_P_QXI + 1310720,
  WS_P_ZM  = WS_P_LQC + 1310720,
  WS_P_ZC  = WS_P_ZM  + 1310720,
  WS_P_H23 = WS_P_ZC  + 1310720,   // 128*5*4096
  WS_P_H3  = WS_P_H23 + 2621440,
  WS_P_RM  = WS_P_H3  + 1310720,   // 64*5*4097
  WS_P_RC  = WS_P_RM  + 1311040,
  WS_P_XM  = WS_P_RC  + 1311040,
  WS_P_XC  = WS_P_XM  + 1310720,
  WS_END   = WS_P_XC  + 1310720    // ~63 MB
};

#define GCOLS 128   // output cols per block
#define GK    64    // k rows per block (NS = din/GK)
#define WROWS 16    // k rows per wave

typedef float f2v __attribute__((ext_vector_type(2)));

__device__ inline float ntl(const float* p) { return __builtin_nontemporal_load(p); }

__device__ inline float wave_sum(float v) {
  #pragma unroll
  for (int o = 32; o > 0; o >>= 1) v += __shfl_down(v, o, 64);
  return v;
}

// ---------------- GEMM body (R15-proven: NT weight loads) ----------------
// 4 waves/block; wave w owns k-rows [w*16,(w+1)*16): wave-local staging (no
// barrier), 16 nontemporal float2 weight rows, single-barrier LDS combine;
// wave 0 writes the NS=64 split partial (no atomics, no fences).
// PROLOG: 0 raw p0 ; 2 relu(p0[b]*p1[k]+p2[k]) ; 3 concat(x=p0, z=p1)
template<int PROLOG, int DUAL, int ALIGNED>
__device__ __forceinline__ void gemm5_body(
    float* sx, float* red, int bx, int by,
    const float* __restrict__ p0, const float* __restrict__ p1,
    const float* __restrict__ p2,
    const float* __restrict__ Wa, const float* __restrict__ Wb,
    float* __restrict__ Pa,       float* __restrict__ Pb,
    int din, int dout)
{
  const int tid  = threadIdx.x;
  const int lane = tid & 63;
  const int wv   = tid >> 6;
  const long i0  = (long)by * GK;
  const long r0  = i0 + (long)wv * WROWS;

  // wave-local stage: this wave's 5x16 activation tile (no cross-wave dep)
  float* sw = sx + wv * 80;
  for (int t = lane; t < B5 * WROWS; t += 64) {
    int b  = t >> 4;
    int il = t & 15;
    int i  = (int)(r0 + il);
    float v;
    if (PROLOG == 0)      v = p0[(long)b * din + i];
    else if (PROLOG == 2) v = fmaxf(p0[b] * p1[i] + p2[i], 0.f);
    else                  v = (i < DX) ? p0[(long)b * DX + i] : p1[(long)b * DT + (i - DX)];
    sw[t] = v;
  }
  // wave-internal ds_write -> ds_read ordering: no __syncthreads needed

  const long o0 = (long)bx * GCOLS + lane * 2;
  const bool v0 = (o0 < dout);
  const bool v1 = (o0 + 1 < dout);

  float accA[B5][2] = {};
  float accB[B5][2] = {};
  const float* wa = Wa + r0 * dout + o0;
  const float* wb = DUAL ? (Wb + r0 * dout + o0) : nullptr;

  #pragma unroll 8
  for (int il = 0; il < WROWS; ++il) {
    float w0a, w1a, w0b = 0.f, w1b = 0.f;
    if (ALIGNED) {
      f2v ta = __builtin_nontemporal_load((const f2v*)wa);
      w0a = ta.x; w1a = ta.y;
      if (DUAL) {
        f2v tb = __builtin_nontemporal_load((const f2v*)wb);
        w0b = tb.x; w1b = tb.y;
      }
    } else {
      w0a = v0 ? ntl(wa) : 0.f;
      w1a = v1 ? ntl(wa + 1) : 0.f;
      if (DUAL) {
        w0b = v0 ? ntl(wb) : 0.f;
        w1b = v1 ? ntl(wb + 1) : 0.f;
      }
    }
    #pragma unroll
    for (int b = 0; b < B5; ++b) {
      float xv = sw[b * WROWS + il];
      accA[b][0] += xv * w0a; accA[b][1] += xv * w1a;
      if (DUAL) { accB[b][0] += xv * w0b; accB[b][1] += xv * w1b; }
    }
    wa += dout; if (DUAL) wb += dout;
  }

  // single-barrier combine: waves 1..3 dump, wave 0 sums + writes
  const int NJ = DUAL ? 20 : 10;
  if (wv > 0) {
    float* rr = red + (long)(wv - 1) * NJ * 64 + lane;
    #pragma unroll
    for (int b = 0; b < B5; ++b) {
      rr[(b*2)*64] = accA[b][0]; rr[(b*2+1)*64] = accA[b][1];
      if (DUAL) { rr[(10+b*2)*64] = accB[b][0]; rr[(10+b*2+1)*64] = accB[b][1]; }
    }
  }
  __syncthreads();
  if (wv == 0) {
    #pragma unroll
    for (int w2 = 0; w2 < 3; ++w2) {
      const float* rr = red + (long)w2 * NJ * 64 + lane;
      #pragma unroll
      for (int b = 0; b < B5; ++b) {
        accA[b][0] += rr[(b*2)*64]; accA[b][1] += rr[(b*2+1)*64];
        if (DUAL) { accB[b][0] += rr[(10+b*2)*64]; accB[b][1] += rr[(10+b*2+1)*64]; }
      }
    }
    if (v0) {
      #pragma unroll
      for (int b = 0; b < B5; ++b) {
        float* pa = Pa + ((long)by * B5 + b) * dout + o0;
        if (ALIGNED) *(float2*)pa = make_float2(accA[b][0], accA[b][1]);
        else { pa[0] = accA[b][0]; if (v1) pa[1] = accA[b][1]; }
        if (DUAL) {
          float* pb = Pb + ((long)by * B5 + b) * dout + o0;
          if (ALIGNED) *(float2*)pb = make_float2(accB[b][0], accB[b][1]);
          else { pb[0] = accB[b][0]; if (v1) pb[1] = accB[b][1]; }
        }
      }
    }
  }
}

template<int PROLOG, int DUAL, int ALIGNED>
__global__ __launch_bounds__(256) void gemm5(
    const float* __restrict__ p0, const float* __restrict__ p1,
    const float* __restrict__ p2,
    const float* __restrict__ Wa, const float* __restrict__ Wb,
    float* __restrict__ Pa,       float* __restrict__ Pb,
    int din, int dout)
{
  __shared__ float sx[4 * 80];
  __shared__ float red[3 * 20 * 64];
  gemm5_body<PROLOG, DUAL, ALIGNED>(sx, red, blockIdx.x, blockIdx.y,
      p0, p1, p2, Wa, Wb, Pa, Pb, din, dout);
}

// merged G4 (concat(x,z)@W23: 32x128=4096) + G6 (z@W3: 2048)
__global__ __launch_bounds__(256) void gemm5_G46(
    const float* __restrict__ x,   const float* __restrict__ z,
    const float* __restrict__ W23, float* __restrict__ P23,
    const float* __restrict__ W3,  float* __restrict__ P3)
{
  __shared__ float sx[4 * 80];
  __shared__ float red[3 * 20 * 64];
  int id = blockIdx.x;
  if (id < 4096) {
    gemm5_body<3, 0, 1>(sx, red, id & 31, id >> 5, x, z, nullptr,
                        W23, nullptr, P23, nullptr, 8192, 4096);
  } else {
    id -= 4096;
    gemm5_body<0, 0, 1>(sx, red, id & 31, id >> 5, z, nullptr, nullptr,
                        W3, nullptr, P3, nullptr, 4096, 4096);
  }
}

// merged G5 (act23@[W24,W25], dout=4097: 33x64=2112) + G7 (act3@[W31,W32]: 2048)
__global__ __launch_bounds__(256) void gemm5_G57(
    const float* __restrict__ act23,
    const float* __restrict__ W24, const float* __restrict__ W25,
    float* __restrict__ PRM,       float* __restrict__ PRC,
    const float* __restrict__ act3,
    const float* __restrict__ W31, const float* __restrict__ W32,
    float* __restrict__ PXM,       float* __restrict__ PXC)
{
  __shared__ float sx[4 * 80];
  __shared__ float red[3 * 20 * 64];
  int id = blockIdx.x;
  if (id < 2112) {
    gemm5_body<0, 1, 0>(sx, red, id % 33, id / 33, act23, nullptr, nullptr,
                        W24, W25, PRM, PRC, 4096, 4097);
  } else {
    id -= 2112;
    gemm5_body<0, 1, 1>(sx, red, id & 31, id >> 5, act3, nullptr, nullptr,
                        W31, W32, PXM, PXC, 4096, 4096);
  }
}

// ---------------- act reductions (NT partial reads; also zero control floats) ----------
__global__ __launch_bounds__(256) void k_act1(
    const float* __restrict__ P, const float* __restrict__ bias, float* __restrict__ act,
    float* __restrict__ ctrl)
{
  if (blockIdx.x == 0 && threadIdx.x < WS_ZERO_END) ctrl[threadIdx.x] = 0.f;
  int idx = blockIdx.x * 256 + threadIdx.x;          // < 20480
  int b = idx >> 12, col = idx & (DT - 1);
  const float* pp = P + (long)b * DT + col;
  float s = 0.f;
  #pragma unroll 8
  for (int ks = 0; ks < 64; ++ks) s += ntl(pp + (long)ks * (B5 * DT));
  act[idx] = fmaxf(s + bias[col], 0.f);
}

__global__ __launch_bounds__(256) void k_act23(
    const float* __restrict__ P23, const float* __restrict__ b23, float* __restrict__ act23,
    const float* __restrict__ P3,  const float* __restrict__ b3,  float* __restrict__ act3)
{
  int idx = blockIdx.x * 256 + threadIdx.x;
  if (idx < B5 * DT) {
    int b = idx >> 12, col = idx & (DT - 1);
    const float* pp = P23 + (long)b * DT + col;
    float s = 0.f;
    #pragma unroll 8
    for (int ks = 0; ks < 128; ++ks) s += ntl(pp + (long)ks * (B5 * DT));
    act23[idx] = fmaxf(s + b23[col], 0.f);
  } else {
    int j = idx - B5 * DT;
    int b = j >> 12, col = j & (DT - 1);
    const float* pp = P3 + (long)b * DT + col;
    float s = 0.f;
    #pragma unroll 8
    for (int ks = 0; ks < 64; ++ks) s += ntl(pp + (long)ks * (B5 * DT));
    act3[j] = fmaxf(s + b3[col], 0.f);
  }
}

// ---------------- fused: xi (blocks 0-79) + ARD (80-129) + GP solve ----------------
__global__ __launch_bounds__(256) void k_xiard(
    const float* __restrict__ Pq, const float* __restrict__ Pl,
    const float* __restrict__ b11, const float* __restrict__ b12,
    const float* __restrict__ eps_xi,
    const float* __restrict__ s,   const float* __restrict__ w,
    const float* __restrict__ sigma,
    const float* __restrict__ t_in, const float* __restrict__ eps_f,
    float* __restrict__ qf, float* __restrict__ lf, float* __restrict__ xiv,
    float* __restrict__ Kss, float* __restrict__ Kxs,
    int* __restrict__ cnt_xi, int* __restrict__ cnt_ard,
    float* __restrict__ fv, float* __restrict__ qfm, float* __restrict__ qfc)
{
  if (blockIdx.x < 80) {
    int idx = blockIdx.x * 256 + threadIdx.x;          // < 20480
    int b = idx >> 12, col = idx & (DT - 1);
    const float* pq = Pq + (long)b * DT + col;
    const float* pl = Pl + (long)b * DT + col;
    float sq = 0.f, sl = 0.f;
    #pragma unroll 8
    for (int ks = 0; ks < 64; ++ks) {
      sq += ntl(pq + (long)ks * (B5 * DT));
      sl += ntl(pl + (long)ks * (B5 * DT));
    }
    float qm = sq + b11[col];
    float lq = sl + b12[col];
    qf[idx] = qm; lf[idx] = lq;
    xiv[idx] = expf(0.5f * lq) * eps_xi[idx] + qm;
    __threadfence();
    __syncthreads();
    if (threadIdx.x == 0) atomicAdd(cnt_xi, 1);
    return;
  }

  const int bid = blockIdx.x - 80;
  const bool xs = (bid >= 25);
  int q = xs ? bid - 25 : bid;
  const int i = q / 5, j = q % 5;

  if (xs) {  // K_xs needs xi: wait for the 80 xi blocks (all 130 co-resident)
    if (threadIdx.x == 0) { while (atomicAdd(cnt_xi, 0) < 80) {} }
    __syncthreads();
    __threadfence();
  }
  const float* aa = xs ? (xiv + (long)i * DT) : (s + (long)i * DT);
  const float* bb = s + (long)j * DT;

  float sum = 0.f;
  for (int t = threadIdx.x; t < DT; t += 256) {
    float d = aa[t] - bb[t];
    sum += w[t] * d * d;
  }
  sum = wave_sum(sum);
  __shared__ float red4[4];
  int lane = threadIdx.x & 63, wv = threadIdx.x >> 6;
  if (lane == 0) red4[wv] = sum;
  __syncthreads();

  if (threadIdx.x == 0) {
    float tot = red4[0] + red4[1] + red4[2] + red4[3];
    float sg = sigma[0];
    float K = sg * sg * expf(-0.5f * tot);
    (xs ? Kxs : Kss)[i * 5 + j] = K;
    __threadfence();
    int old = atomicAdd(cnt_ard, 1);
    if (old == 49) {
      __threadfence();
      double M[5][5], Inv[5][5];
      for (int a = 0; a < 5; ++a)
        for (int b = 0; b < 5; ++b) { M[a][b] = Kss[a * 5 + b]; Inv[a][b] = (a == b) ? 1.0 : 0.0; }
      for (int c = 0; c < 5; ++c) {
        int p = c; double best = fabs(M[c][c]);
        for (int r = c + 1; r < 5; ++r) if (fabs(M[r][c]) > best) { best = fabs(M[r][c]); p = r; }
        if (p != c)
          for (int k = 0; k < 5; ++k) {
            double tm = M[c][k]; M[c][k] = M[p][k]; M[p][k] = tm;
            tm = Inv[c][k]; Inv[c][k] = Inv[p][k]; Inv[p][k] = tm;
          }
        double piv = 1.0 / M[c][c];
        for (int k = 0; k < 5; ++k) { M[c][k] *= piv; Inv[c][k] *= piv; }
        for (int r = 0; r < 5; ++r) if (r != c) {
          double m = M[r][c];
          for (int k = 0; k < 5; ++k) { M[r][k] -= m * M[c][k]; Inv[r][k] -= m * Inv[c][k]; }
        }
      }
      double kk[5][5];
      for (int a = 0; a < 5; ++a)
        for (int b = 0; b < 5; ++b) {
          double acc = 0.0;
          for (int k = 0; k < 5; ++k) acc += (double)Kxs[a * 5 + k] * Inv[k][b];
          kk[a][b] = acc;
        }
      double sg2 = (double)sg * (double)sg;
      for (int a = 0; a < 5; ++a) {
        double qm = 0.0, qc = sg2;
        for (int b = 0; b < 5; ++b) { qm += kk[a][b] * (double)t_in[b]; qc -= kk[a][b] * (double)Kxs[a * 5 + b]; }
        if (qc < 1e-12) qc = 1e-12;
        qfm[a] = (float)qm;
        qfc[a] = (float)qc;
        fv[a]  = sqrtf((float)qc) * eps_f[a] + (float)qm;
      }
    }
  }
}

// ---------------- k_z ----------------
__global__ __launch_bounds__(256) void k_z(
    const float* __restrict__ Pm, const float* __restrict__ Pc,
    const float* __restrict__ b21, const float* __restrict__ b22,
    const float* __restrict__ eps_z,
    float* __restrict__ out_zm, float* __restrict__ out_zc,
    float* __restrict__ zv, float* __restrict__ kld1sum)
{
  int idx = blockIdx.x * 256 + threadIdx.x;
  float term = 0.f;
  if (idx < B5 * DT) {
    int b = idx >> 12, col = idx & (DT - 1);
    const float* pm = Pm + (long)b * DT + col;
    const float* pc = Pc + (long)b * DT + col;
    float sm = 0.f, sc = 0.f;
    #pragma unroll 8
    for (int ks = 0; ks < 64; ++ks) {
      sm += ntl(pm + (long)ks * (B5 * DT));
      sc += ntl(pc + (long)ks * (B5 * DT));
    }
    float zm = sm + b21[col];
    float zc = sc + b22[col];
    out_zm[idx] = zm; out_zc[idx] = zc;
    zv[idx] = expf(0.5f * zc) * eps_z[idx] + zm;
    term = -zc - 1.f + expf(zc) + zm * zm;
  }
  term = wave_sum(term);
  if ((threadIdx.x & 63) == 0) atomicAdd(kld1sum, term);
}

// ---------------- FIN ----------------
__global__ __launch_bounds__(256) void k_fin(
    const float* __restrict__ Prm, const float* __restrict__ Prc,
    const float* __restrict__ b24, const float* __restrict__ b25,
    const float* __restrict__ qxi, const float* __restrict__ lqc,
    const float* __restrict__ qfm, const float* __restrict__ qfc,
    const float* __restrict__ Pxm, const float* __restrict__ Pxc,
    const float* __restrict__ b31, const float* __restrict__ b32,
    const float* __restrict__ x,
    float* __restrict__ out_xm, float* __restrict__ out_xc,
    float* __restrict__ sums, int* __restrict__ cnt, float* __restrict__ out01)
{
  const int gtid = blockIdx.x * 256 + threadIdx.x;
  float t2 = 0.f, t3 = 0.f;
  if (gtid < B5 * DR) {
    int b = gtid / DR, col = gtid % DR;
    const float* pm = Prm + (long)b * DR + col;
    const float* pc = Prc + (long)b * DR + col;
    float sm = 0.f, sc = 0.f;
    #pragma unroll 8
    for (int ks = 0; ks < 64; ++ks) {
      sm += ntl(pm + (long)ks * (B5 * DR));
      sc += ntl(pc + (long)ks * (B5 * DR));
    }
    float rm = sm + b24[col];
    float rc = sc + b25[col];
    float qm, qc;
    if (col < DT) { qm = qxi[(long)b * DT + col]; qc = lqc[(long)b * DT + col]; }
    else          { qm = qfm[b]; qc = logf(qfc[b]); }
    float d = qm - rm;
    t2 = rc - qc - 1.f + expf(qc - rc) + d * d * expf(-rc);
  } else {
    int idx = gtid - B5 * DR;
    if (idx < B5 * DX) {
      int b = idx >> 12, col = idx & (DX - 1);
      const float* pm = Pxm + (long)b * DX + col;
      const float* pc = Pxc + (long)b * DX + col;
      float sm = 0.f, sc = 0.f;
      #pragma unroll 8
      for (int ks = 0; ks < 64; ++ks) {
        sm += ntl(pm + (long)ks * (B5 * DX));
        sc += ntl(pc + (long)ks * (B5 * DX));
      }
      float xm = sm + b31[col];
      float xc = sc + b32[col];
      out_xm[idx] = xm; out_xc[idx] = xc;
      float d = x[idx] - xm;
      t3 = 1.14472988584940017f + xc + expf(-xc) * d * d;  // ln(pi) + ...
    }
  }
  t2 = wave_sum(t2);
  t3 = wave_sum(t3);
  if ((threadIdx.x & 63) == 0) {
    if (t2 != 0.f) atomicAdd(&sums[1], t2);
    if (t3 != 0.f) atomicAdd(&sums[2], t3);
  }
  __syncthreads();
  if (threadIdx.x == 0) {
    __threadfence();
    int old = atomicAdd(cnt, 1);
    if (old == (int)gridDim.x - 1) {
      __threadfence();
      out01[0] = 0.5f * (sums[0] + sums[1]) / (float)B5;
      out01[1] = 0.5f * sums[2] / (float)B5;
    }
  }
}

// ---------------- launch ----------------
extern "C" void kernel_launch(void* const* d_in, const int* in_sizes, int n_in,
                              void* d_out, int out_size, void* d_ws, size_t ws_size,
                              hipStream_t stream)
{
  const float* x      = (const float*)d_in[0];
  const float* eps_xi = (const float*)d_in[1];
  const float* eps_f  = (const float*)d_in[2];
  const float* eps_z  = (const float*)d_in[3];
  const float* W1  = (const float*)d_in[4];  const float* b1  = (const float*)d_in[5];
  const float* W11 = (const float*)d_in[6];  const float* b11 = (const float*)d_in[7];
  const float* W12 = (const float*)d_in[8];  const float* b12 = (const float*)d_in[9];
  const float* W2  = (const float*)d_in[10]; const float* b2  = (const float*)d_in[11];
  const float* W21 = (const float*)d_in[12]; const float* b21 = (const float*)d_in[13];
  const float* W22 = (const float*)d_in[14]; const float* b22 = (const float*)d_in[15];
  const float* W23 = (const float*)d_in[16]; const float* b23 = (const float*)d_in[17];
  const float* W24 = (const float*)d_in[18]; const float* b24 = (const float*)d_in[19];
  const float* W25 = (const float*)d_in[20]; const float* b25 = (const float*)d_in[21];
  const float* W3  = (const float*)d_in[22]; const float* b3  = (const float*)d_in[23];
  const float* W31 = (const float*)d_in[24]; const float* b31 = (const float*)d_in[25];
  const float* W32 = (const float*)d_in[26]; const float* b32 = (const float*)d_in[27];
  const float* s     = (const float*)d_in[28];
  const float* t     = (const float*)d_in[29];
  const float* sigma = (const float*)d_in[30];
  const float* w     = (const float*)d_in[31];

  float* ws  = (float*)d_ws;
  float* out = (float*)d_out;

  dim3 blk(256);

  // G1: h1 partials = x @ W1                    (2048 blocks)
  gemm5<0,0,1><<<dim3(32,64), blk, 0, stream>>>(
      x, nullptr, nullptr, W1, nullptr, ws + WS_P_H1, nullptr, 4096, 4096);
  // act1 = relu(sum P_H1 + b1)  (+ zero control floats)
  k_act1<<<80, blk, 0, stream>>>(ws + WS_P_H1, b1, ws + WS_ACT1, ws);
  // G2: qxi/lqc partials = act1 @ [W11, W12]
  gemm5<0,1,1><<<dim3(32,64), blk, 0, stream>>>(
      ws + WS_ACT1, nullptr, nullptr, W11, W12, ws + WS_P_QXI, ws + WS_P_LQC, 4096, 4096);
  // fused xi + ARD + GP solve    (130 blocks, co-resident counter handoff)
  k_xiard<<<130, blk, 0, stream>>>(
      ws + WS_P_QXI, ws + WS_P_LQC, b11, b12, eps_xi,
      s, w, sigma, t, eps_f,
      ws + WS_QXI_F, ws + WS_LQC_F, ws + WS_XIV,
      ws + WS_KSS, ws + WS_KXS,
      (int*)(ws + WS_CNT_XI), (int*)(ws + WS_CNT_ARD),
      ws + WS_F, ws + WS_QFM, ws + WS_QFC);
  // G3: zm/zc partials = relu(f*W2+b2) @ [W21, W22]
  gemm5<2,1,1><<<dim3(32,64), blk, 0, stream>>>(
      ws + WS_F, W2, b2, W21, W22, ws + WS_P_ZM, ws + WS_P_ZC, 4096, 4096);
  // k_z: finalize zm/zc + sample z + kld1
  k_z<<<80, blk, 0, stream>>>(
      ws + WS_P_ZM, ws + WS_P_ZC, b21, b22, eps_z,
      out + 2, out + 2 + 20480, ws + WS_Z, ws + WS_SUMS);
  // G4+G6: h23 partials ; h3 partials          (6144 blocks)
  gemm5_G46<<<6144, blk, 0, stream>>>(
      x, ws + WS_Z, W23, ws + WS_P_H23, W3, ws + WS_P_H3);
  // act23 / act3
  k_act23<<<160, blk, 0, stream>>>(
      ws + WS_P_H23, b23, ws + WS_ACT23, ws + WS_P_H3, b3, ws + WS_ACT3);
  // G5+G7: rm/rc partials ; xm/xc partials     (4160 blocks)
  gemm5_G57<<<4160, blk, 0, stream>>>(
      ws + WS_ACT23, W24, W25, ws + WS_P_RM, ws + WS_P_RC,
      ws + WS_ACT3,  W31, W32, ws + WS_P_XM, ws + WS_P_XC);
  // FIN
  k_fin<<<161, blk, 0, stream>>>(
      ws + WS_P_RM, ws + WS_P_RC, b24, b25,
      ws + WS_QXI_F, ws + WS_LQC_F,
      ws + WS_QFM, ws + WS_QFC,
      ws + WS_P_XM, ws + WS_P_XC, b31, b32, x,
      out + 2 + 40960, out + 2 + 61440,
      ws + WS_SUMS, (int*)(ws + WS_CNT_FIN), out);
}

// Round 17
// 244.066 us; speedup vs baseline: 1.0361x; 1.0361x over previous
//
#include <hip/hip_runtime.h>
#include <math.h>

#define B5 5
#define DX 4096
#define DT 4096
#define DR 4097   // T + D

// ---------------- workspace layout (floats) ----------------
enum {
  WS_SUMS  = 0,                    // [kld1, kld2, nll]
  WS_CNT_XI  = 3,
  WS_CNT_FIN = 4,
  WS_CNT_ARD = 5,
  WS_ZERO_END = 8,
  WS_ACT1  = 16,                   // relu(h1+b1)   (20480)
  WS_ACT23 = WS_ACT1  + 20480,
  WS_ACT3  = WS_ACT23 + 20480,
  WS_QXI_F = WS_ACT3  + 20480,
  WS_LQC_F = WS_QXI_F + 20480,
  WS_XIV   = WS_LQC_F + 20480,
  WS_Z     = WS_XIV   + 20480,
  WS_KSS   = WS_Z     + 20480,     // 25 (pad 32)
  WS_KXS   = WS_KSS + 32,
  WS_F     = WS_KXS + 32,
  WS_QFM   = WS_F   + 8,
  WS_QFC   = WS_QFM + 8,
  WS_PART  = 143472,               // 16-aligned
  // partials [ks][b][dout], NS=64 (H23: 128)
  WS_P_H1  = WS_PART,
  WS_P_QXI = WS_P_H1  + 1310720,
  WS_P_LQC = WS_P_QXI + 1310720,
  WS_P_ZM  = WS_P_LQC + 1310720,
  WS_P_ZC  = WS_P_ZM  + 1310720,
  WS_P_H23 = WS_P_ZC  + 1310720,   // 128*5*4096
  WS_P_H3  = WS_P_H23 + 2621440,
  WS_P_RM  = WS_P_H3  + 1310720,   // 64*5*4097
  WS_P_RC  = WS_P_RM  + 1311040,
  WS_P_XM  = WS_P_RC  + 1311040,
  WS_P_XC  = WS_P_XM  + 1310720,
  WS_END   = WS_P_XC  + 1310720    // ~63 MB
};

#define GCOLS 128   // output cols per block
#define GK    64    // k rows per block (NS = din/GK)
#define WROWS 16    // k rows per wave

typedef float f2v __attribute__((ext_vector_type(2)));

__device__ inline float ntl(const float* p) { return __builtin_nontemporal_load(p); }

__device__ inline float wave_sum(float v) {
  #pragma unroll
  for (int o = 32; o > 0; o >>= 1) v += __shfl_down(v, o, 64);
  return v;
}

// ---------------- GEMM body (R15-proven: NT weight loads) ----------------
// 4 waves/block; wave w owns k-rows [w*16,(w+1)*16): wave-local staging (no
// barrier), 16 nontemporal float2 weight rows, single-barrier LDS combine;
// wave 0 writes the NS=64 split partial (no atomics, no fences).
// PROLOG: 0 raw p0 ; 2 relu(p0[b]*p1[k]+p2[k]) ; 3 concat(x=p0, z=p1)
template<int PROLOG, int DUAL, int ALIGNED>
__device__ __forceinline__ void gemm5_body(
    float* sx, float* red, int bx, int by,
    const float* __restrict__ p0, const float* __restrict__ p1,
    const float* __restrict__ p2,
    const float* __restrict__ Wa, const float* __restrict__ Wb,
    float* __restrict__ Pa,       float* __restrict__ Pb,
    int din, int dout)
{
  const int tid  = threadIdx.x;
  const int lane = tid & 63;
  const int wv   = tid >> 6;
  const long i0  = (long)by * GK;
  const long r0  = i0 + (long)wv * WROWS;

  // wave-local stage: this wave's 5x16 activation tile (no cross-wave dep)
  float* sw = sx + wv * 80;
  for (int t = lane; t < B5 * WROWS; t += 64) {
    int b  = t >> 4;
    int il = t & 15;
    int i  = (int)(r0 + il);
    float v;
    if (PROLOG == 0)      v = p0[(long)b * din + i];
    else if (PROLOG == 2) v = fmaxf(p0[b] * p1[i] + p2[i], 0.f);
    else                  v = (i < DX) ? p0[(long)b * DX + i] : p1[(long)b * DT + (i - DX)];
    sw[t] = v;
  }
  // wave-internal ds_write -> ds_read ordering: no __syncthreads needed

  const long o0 = (long)bx * GCOLS + lane * 2;
  const bool v0 = (o0 < dout);
  const bool v1 = (o0 + 1 < dout);

  float accA[B5][2] = {};
  float accB[B5][2] = {};
  const float* wa = Wa + r0 * dout + o0;
  const float* wb = DUAL ? (Wb + r0 * dout + o0) : nullptr;

  #pragma unroll 8
  for (int il = 0; il < WROWS; ++il) {
    float w0a, w1a, w0b = 0.f, w1b = 0.f;
    if (ALIGNED) {
      f2v ta = __builtin_nontemporal_load((const f2v*)wa);
      w0a = ta.x; w1a = ta.y;
      if (DUAL) {
        f2v tb = __builtin_nontemporal_load((const f2v*)wb);
        w0b = tb.x; w1b = tb.y;
      }
    } else {
      w0a = v0 ? ntl(wa) : 0.f;
      w1a = v1 ? ntl(wa + 1) : 0.f;
      if (DUAL) {
        w0b = v0 ? ntl(wb) : 0.f;
        w1b = v1 ? ntl(wb + 1) : 0.f;
      }
    }
    #pragma unroll
    for (int b = 0; b < B5; ++b) {
      float xv = sw[b * WROWS + il];
      accA[b][0] += xv * w0a; accA[b][1] += xv * w1a;
      if (DUAL) { accB[b][0] += xv * w0b; accB[b][1] += xv * w1b; }
    }
    wa += dout; if (DUAL) wb += dout;
  }

  // single-barrier combine: waves 1..3 dump, wave 0 sums + writes
  const int NJ = DUAL ? 20 : 10;
  if (wv > 0) {
    float* rr = red + (long)(wv - 1) * NJ * 64 + lane;
    #pragma unroll
    for (int b = 0; b < B5; ++b) {
      rr[(b*2)*64] = accA[b][0]; rr[(b*2+1)*64] = accA[b][1];
      if (DUAL) { rr[(10+b*2)*64] = accB[b][0]; rr[(10+b*2+1)*64] = accB[b][1]; }
    }
  }
  __syncthreads();
  if (wv == 0) {
    #pragma unroll
    for (int w2 = 0; w2 < 3; ++w2) {
      const float* rr = red + (long)w2 * NJ * 64 + lane;
      #pragma unroll
      for (int b = 0; b < B5; ++b) {
        accA[b][0] += rr[(b*2)*64]; accA[b][1] += rr[(b*2+1)*64];
        if (DUAL) { accB[b][0] += rr[(10+b*2)*64]; accB[b][1] += rr[(10+b*2+1)*64]; }
      }
    }
    if (v0) {
      #pragma unroll
      for (int b = 0; b < B5; ++b) {
        float* pa = Pa + ((long)by * B5 + b) * dout + o0;
        if (ALIGNED) *(float2*)pa = make_float2(accA[b][0], accA[b][1]);
        else { pa[0] = accA[b][0]; if (v1) pa[1] = accA[b][1]; }
        if (DUAL) {
          float* pb = Pb + ((long)by * B5 + b) * dout + o0;
          if (ALIGNED) *(float2*)pb = make_float2(accB[b][0], accB[b][1]);
          else { pb[0] = accB[b][0]; if (v1) pb[1] = accB[b][1]; }
        }
      }
    }
  }
}

template<int PROLOG, int DUAL, int ALIGNED>
__global__ __launch_bounds__(256) void gemm5(
    const float* __restrict__ p0, const float* __restrict__ p1,
    const float* __restrict__ p2,
    const float* __restrict__ Wa, const float* __restrict__ Wb,
    float* __restrict__ Pa,       float* __restrict__ Pb,
    int din, int dout)
{
  __shared__ float sx[4 * 80];
  __shared__ float red[3 * 20 * 64];
  gemm5_body<PROLOG, DUAL, ALIGNED>(sx, red, blockIdx.x, blockIdx.y,
      p0, p1, p2, Wa, Wb, Pa, Pb, din, dout);
}

// merged G4 (concat(x,z)@W23: 32x128=4096) + G6 (z@W3: 2048)
__global__ __launch_bounds__(256) void gemm5_G46(
    const float* __restrict__ x,   const float* __restrict__ z,
    const float* __restrict__ W23, float* __restrict__ P23,
    const float* __restrict__ W3,  float* __restrict__ P3)
{
  __shared__ float sx[4 * 80];
  __shared__ float red[3 * 20 * 64];
  int id = blockIdx.x;
  if (id < 4096) {
    gemm5_body<3, 0, 1>(sx, red, id & 31, id >> 5, x, z, nullptr,
                        W23, nullptr, P23, nullptr, 8192, 4096);
  } else {
    id -= 4096;
    gemm5_body<0, 0, 1>(sx, red, id & 31, id >> 5, z, nullptr, nullptr,
                        W3, nullptr, P3, nullptr, 4096, 4096);
  }
}

// merged G5 (act23@[W24,W25], dout=4097: 33x64=2112) + G7 (act3@[W31,W32]: 2048)
__global__ __launch_bounds__(256) void gemm5_G57(
    const float* __restrict__ act23,
    const float* __restrict__ W24, const float* __restrict__ W25,
    float* __restrict__ PRM,       float* __restrict__ PRC,
    const float* __restrict__ act3,
    const float* __restrict__ W31, const float* __restrict__ W32,
    float* __restrict__ PXM,       float* __restrict__ PXC)
{
  __shared__ float sx[4 * 80];
  __shared__ float red[3 * 20 * 64];
  int id = blockIdx.x;
  if (id < 2112) {
    gemm5_body<0, 1, 0>(sx, red, id % 33, id / 33, act23, nullptr, nullptr,
                        W24, W25, PRM, PRC, 4096, 4097);
  } else {
    id -= 2112;
    gemm5_body<0, 1, 1>(sx, red, id & 31, id >> 5, act3, nullptr, nullptr,
                        W31, W32, PXM, PXC, 4096, 4096);
  }
}

// ---------------- act reductions (NT partial reads; also zero control floats) ----------
__global__ __launch_bounds__(256) void k_act1(
    const float* __restrict__ P, const float* __restrict__ bias, float* __restrict__ act,
    float* __restrict__ ctrl)
{
  if (blockIdx.x == 0 && threadIdx.x < WS_ZERO_END) ctrl[threadIdx.x] = 0.f;
  int idx = blockIdx.x * 256 + threadIdx.x;          // < 20480
  int b = idx >> 12, col = idx & (DT - 1);
  const float* pp = P + (long)b * DT + col;
  float s = 0.f;
  #pragma unroll 8
  for (int ks = 0; ks < 64; ++ks) s += ntl(pp + (long)ks * (B5 * DT));
  act[idx] = fmaxf(s + bias[col], 0.f);
}

__global__ __launch_bounds__(256) void k_act23(
    const float* __restrict__ P23, const float* __restrict__ b23, float* __restrict__ act23,
    const float* __restrict__ P3,  const float* __restrict__ b3,  float* __restrict__ act3)
{
  int idx = blockIdx.x * 256 + threadIdx.x;
  if (idx < B5 * DT) {
    int b = idx >> 12, col = idx & (DT - 1);
    const float* pp = P23 + (long)b * DT + col;
    float s = 0.f;
    #pragma unroll 8
    for (int ks = 0; ks < 128; ++ks) s += ntl(pp + (long)ks * (B5 * DT));
    act23[idx] = fmaxf(s + b23[col], 0.f);
  } else {
    int j = idx - B5 * DT;
    int b = j >> 12, col = j & (DT - 1);
    const float* pp = P3 + (long)b * DT + col;
    float s = 0.f;
    #pragma unroll 8
    for (int ks = 0; ks < 64; ++ks) s += ntl(pp + (long)ks * (B5 * DT));
    act3[j] = fmaxf(s + b3[col], 0.f);
  }
}

// ---------------- k_xi: reduce qxi/lqc partials (NT), finalize, sample xi ----------------
__global__ __launch_bounds__(256) void k_xi(
    const float* __restrict__ Pq, const float* __restrict__ Pl,
    const float* __restrict__ b11, const float* __restrict__ b12,
    const float* __restrict__ eps_xi,
    float* __restrict__ qf, float* __restrict__ lf, float* __restrict__ xiv)
{
  int idx = blockIdx.x * 256 + threadIdx.x;
  if (idx >= B5 * DT) return;
  int b = idx >> 12, col = idx & (DT - 1);
  const float* pq = Pq + (long)b * DT + col;
  const float* pl = Pl + (long)b * DT + col;
  float sq = 0.f, sl = 0.f;
  #pragma unroll 8
  for (int ks = 0; ks < 64; ++ks) {
    sq += ntl(pq + (long)ks * (B5 * DT));
    sl += ntl(pl + (long)ks * (B5 * DT));
  }
  float qm = sq + b11[col];
  float lq = sl + b12[col];
  qf[idx] = qm; lf[idx] = lq;
  xiv[idx] = expf(0.5f * lq) * eps_xi[idx] + qm;
}

// ---------------- ARD + last-block GP solve ----------------
__global__ __launch_bounds__(256) void k_ardgp(
    const float* __restrict__ s,    const float* __restrict__ xiv,
    const float* __restrict__ w,    const float* __restrict__ sigma,
    const float* __restrict__ t_in, const float* __restrict__ eps_f,
    float* __restrict__ Kss, float* __restrict__ Kxs, int* __restrict__ cnt,
    float* __restrict__ fv, float* __restrict__ qfm, float* __restrict__ qfc)
{
  const int bid = blockIdx.x;
  const bool xs = (bid >= 25);
  int q = xs ? bid - 25 : bid;
  const int i = q / 5, j = q % 5;
  const float* aa = xs ? (xiv + (long)i * DT) : (s + (long)i * DT);
  const float* bb = s + (long)j * DT;

  float sum = 0.f;
  for (int t = threadIdx.x; t < DT; t += 256) {
    float d = aa[t] - bb[t];
    sum += w[t] * d * d;
  }
  sum = wave_sum(sum);
  __shared__ float red[4];
  int lane = threadIdx.x & 63, wv = threadIdx.x >> 6;
  if (lane == 0) red[wv] = sum;
  __syncthreads();

  if (threadIdx.x == 0) {
    float tot = red[0] + red[1] + red[2] + red[3];
    float sg = sigma[0];
    float K = sg * sg * expf(-0.5f * tot);
    (xs ? Kxs : Kss)[i * 5 + j] = K;
    __threadfence();
    int old = atomicAdd(cnt, 1);
    if (old == 49) {
      __threadfence();
      double M[5][5], Inv[5][5];
      for (int a = 0; a < 5; ++a)
        for (int b = 0; b < 5; ++b) { M[a][b] = Kss[a * 5 + b]; Inv[a][b] = (a == b) ? 1.0 : 0.0; }
      for (int c = 0; c < 5; ++c) {
        int p = c; double best = fabs(M[c][c]);
        for (int r = c + 1; r < 5; ++r) if (fabs(M[r][c]) > best) { best = fabs(M[r][c]); p = r; }
        if (p != c)
          for (int k = 0; k < 5; ++k) {
            double tm = M[c][k]; M[c][k] = M[p][k]; M[p][k] = tm;
            tm = Inv[c][k]; Inv[c][k] = Inv[p][k]; Inv[p][k] = tm;
          }
        double piv = 1.0 / M[c][c];
        for (int k = 0; k < 5; ++k) { M[c][k] *= piv; Inv[c][k] *= piv; }
        for (int r = 0; r < 5; ++r) if (r != c) {
          double m = M[r][c];
          for (int k = 0; k < 5; ++k) { M[r][k] -= m * M[c][k]; Inv[r][k] -= m * Inv[c][k]; }
        }
      }
      double kk[5][5];
      for (int a = 0; a < 5; ++a)
        for (int b = 0; b < 5; ++b) {
          double acc = 0.0;
          for (int k = 0; k < 5; ++k) acc += (double)Kxs[a * 5 + k] * Inv[k][b];
          kk[a][b] = acc;
        }
      double sg2 = (double)sg * (double)sg;
      for (int a = 0; a < 5; ++a) {
        double qm = 0.0, qc = sg2;
        for (int b = 0; b < 5; ++b) { qm += kk[a][b] * (double)t_in[b]; qc -= kk[a][b] * (double)Kxs[a * 5 + b]; }
        if (qc < 1e-12) qc = 1e-12;
        qfm[a] = (float)qm;
        qfc[a] = (float)qc;
        fv[a]  = sqrtf((float)qc) * eps_f[a] + (float)qm;
      }
    }
  }
}

// ---------------- k_z (NT partial reads) ----------------
__global__ __launch_bounds__(256) void k_z(
    const float* __restrict__ Pm, const float* __restrict__ Pc,
    const float* __restrict__ b21, const float* __restrict__ b22,
    const float* __restrict__ eps_z,
    float* __restrict__ out_zm, float* __restrict__ out_zc,
    float* __restrict__ zv, float* __restrict__ kld1sum)
{
  int idx = blockIdx.x * 256 + threadIdx.x;
  float term = 0.f;
  if (idx < B5 * DT) {
    int b = idx >> 12, col = idx & (DT - 1);
    const float* pm = Pm + (long)b * DT + col;
    const float* pc = Pc + (long)b * DT + col;
    float sm = 0.f, sc = 0.f;
    #pragma unroll 8
    for (int ks = 0; ks < 64; ++ks) {
      sm += ntl(pm + (long)ks * (B5 * DT));
      sc += ntl(pc + (long)ks * (B5 * DT));
    }
    float zm = sm + b21[col];
    float zc = sc + b22[col];
    out_zm[idx] = zm; out_zc[idx] = zc;
    zv[idx] = expf(0.5f * zc) * eps_z[idx] + zm;
    term = -zc - 1.f + expf(zc) + zm * zm;
  }
  term = wave_sum(term);
  if ((threadIdx.x & 63) == 0) atomicAdd(kld1sum, term);
}

// ---------------- FIN (NT partial reads) ----------------
__global__ __launch_bounds__(256) void k_fin(
    const float* __restrict__ Prm, const float* __restrict__ Prc,
    const float* __restrict__ b24, const float* __restrict__ b25,
    const float* __restrict__ qxi, const float* __restrict__ lqc,
    const float* __restrict__ qfm, const float* __restrict__ qfc,
    const float* __restrict__ Pxm, const float* __restrict__ Pxc,
    const float* __restrict__ b31, const float* __restrict__ b32,
    const float* __restrict__ x,
    float* __restrict__ out_xm, float* __restrict__ out_xc,
    float* __restrict__ sums, int* __restrict__ cnt, float* __restrict__ out01)
{
  const int gtid = blockIdx.x * 256 + threadIdx.x;
  float t2 = 0.f, t3 = 0.f;
  if (gtid < B5 * DR) {
    int b = gtid / DR, col = gtid % DR;
    const float* pm = Prm + (long)b * DR + col;
    const float* pc = Prc + (long)b * DR + col;
    float sm = 0.f, sc = 0.f;
    #pragma unroll 8
    for (int ks = 0; ks < 64; ++ks) {
      sm += ntl(pm + (long)ks * (B5 * DR));
      sc += ntl(pc + (long)ks * (B5 * DR));
    }
    float rm = sm + b24[col];
    float rc = sc + b25[col];
    float qm, qc;
    if (col < DT) { qm = qxi[(long)b * DT + col]; qc = lqc[(long)b * DT + col]; }
    else          { qm = qfm[b]; qc = logf(qfc[b]); }
    float d = qm - rm;
    t2 = rc - qc - 1.f + expf(qc - rc) + d * d * expf(-rc);
  } else {
    int idx = gtid - B5 * DR;
    if (idx < B5 * DX) {
      int b = idx >> 12, col = idx & (DX - 1);
      const float* pm = Pxm + (long)b * DX + col;
      const float* pc = Pxc + (long)b * DX + col;
      float sm = 0.f, sc = 0.f;
      #pragma unroll 8
      for (int ks = 0; ks < 64; ++ks) {
        sm += ntl(pm + (long)ks * (B5 * DX));
        sc += ntl(pc + (long)ks * (B5 * DX));
      }
      float xm = sm + b31[col];
      float xc = sc + b32[col];
      out_xm[idx] = xm; out_xc[idx] = xc;
      float d = x[idx] - xm;
      t3 = 1.14472988584940017f + xc + expf(-xc) * d * d;  // ln(pi) + ...
    }
  }
  t2 = wave_sum(t2);
  t3 = wave_sum(t3);
  if ((threadIdx.x & 63) == 0) {
    if (t2 != 0.f) atomicAdd(&sums[1], t2);
    if (t3 != 0.f) atomicAdd(&sums[2], t3);
  }
  __syncthreads();
  if (threadIdx.x == 0) {
    __threadfence();
    int old = atomicAdd(cnt, 1);
    if (old == (int)gridDim.x - 1) {
      __threadfence();
      out01[0] = 0.5f * (sums[0] + sums[1]) / (float)B5;
      out01[1] = 0.5f * sums[2] / (float)B5;
    }
  }
}

// ---------------- launch ----------------
extern "C" void kernel_launch(void* const* d_in, const int* in_sizes, int n_in,
                              void* d_out, int out_size, void* d_ws, size_t ws_size,
                              hipStream_t stream)
{
  const float* x      = (const float*)d_in[0];
  const float* eps_xi = (const float*)d_in[1];
  const float* eps_f  = (const float*)d_in[2];
  const float* eps_z  = (const float*)d_in[3];
  const float* W1  = (const float*)d_in[4];  const float* b1  = (const float*)d_in[5];
  const float* W11 = (const float*)d_in[6];  const float* b11 = (const float*)d_in[7];
  const float* W12 = (const float*)d_in[8];  const float* b12 = (const float*)d_in[9];
  const float* W2  = (const float*)d_in[10]; const float* b2  = (const float*)d_in[11];
  const float* W21 = (const float*)d_in[12]; const float* b21 = (const float*)d_in[13];
  const float* W22 = (const float*)d_in[14]; const float* b22 = (const float*)d_in[15];
  const float* W23 = (const float*)d_in[16]; const float* b23 = (const float*)d_in[17];
  const float* W24 = (const float*)d_in[18]; const float* b24 = (const float*)d_in[19];
  const float* W25 = (const float*)d_in[20]; const float* b25 = (const float*)d_in[21];
  const float* W3  = (const float*)d_in[22]; const float* b3  = (const float*)d_in[23];
  const float* W31 = (const float*)d_in[24]; const float* b31 = (const float*)d_in[25];
  const float* W32 = (const float*)d_in[26]; const float* b32 = (const float*)d_in[27];
  const float* s     = (const float*)d_in[28];
  const float* t     = (const float*)d_in[29];
  const float* sigma = (const float*)d_in[30];
  const float* w     = (const float*)d_in[31];

  float* ws  = (float*)d_ws;
  float* out = (float*)d_out;

  dim3 blk(256);

  // G1: h1 partials = x @ W1                    (2048 blocks)
  gemm5<0,0,1><<<dim3(32,64), blk, 0, stream>>>(
      x, nullptr, nullptr, W1, nullptr, ws + WS_P_H1, nullptr, 4096, 4096);
  // act1 = relu(sum P_H1 + b1)  (+ zero control floats)
  k_act1<<<80, blk, 0, stream>>>(ws + WS_P_H1, b1, ws + WS_ACT1, ws);
  // G2: qxi/lqc partials = act1 @ [W11, W12]
  gemm5<0,1,1><<<dim3(32,64), blk, 0, stream>>>(
      ws + WS_ACT1, nullptr, nullptr, W11, W12, ws + WS_P_QXI, ws + WS_P_LQC, 4096, 4096);
  // k_xi: finalize qxi/lqc + sample xi
  k_xi<<<80, blk, 0, stream>>>(
      ws + WS_P_QXI, ws + WS_P_LQC, b11, b12, eps_xi,
      ws + WS_QXI_F, ws + WS_LQC_F, ws + WS_XIV);
  // ARD + GP solve
  k_ardgp<<<50, blk, 0, stream>>>(
      s, ws + WS_XIV, w, sigma, t, eps_f,
      ws + WS_KSS, ws + WS_KXS, (int*)(ws + WS_CNT_ARD),
      ws + WS_F, ws + WS_QFM, ws + WS_QFC);
  // G3: zm/zc partials = relu(f*W2+b2) @ [W21, W22]
  gemm5<2,1,1><<<dim3(32,64), blk, 0, stream>>>(
      ws + WS_F, W2, b2, W21, W22, ws + WS_P_ZM, ws + WS_P_ZC, 4096, 4096);
  // k_z: finalize zm/zc + sample z + kld1
  k_z<<<80, blk, 0, stream>>>(
      ws + WS_P_ZM, ws + WS_P_ZC, b21, b22, eps_z,
      out + 2, out + 2 + 20480, ws + WS_Z, ws + WS_SUMS);
  // G4+G6: h23 partials ; h3 partials          (6144 blocks)
  gemm5_G46<<<6144, blk, 0, stream>>>(
      x, ws + WS_Z, W23, ws + WS_P_H23, W3, ws + WS_P_H3);
  // act23 / act3
  k_act23<<<160, blk, 0, stream>>>(
      ws + WS_P_H23, b23, ws + WS_ACT23, ws + WS_P_H3, b3, ws + WS_ACT3);
  // G5+G7: rm/rc partials ; xm/xc partials     (4160 blocks)
  gemm5_G57<<<4160, blk, 0, stream>>>(
      ws + WS_ACT23, W24, W25, ws + WS_P_RM, ws + WS_P_RC,
      ws + WS_ACT3,  W31, W32, ws + WS_P_XM, ws + WS_P_XC);
  // FIN
  k_fin<<<161, blk, 0, stream>>>(
      ws + WS_P_RM, ws + WS_P_RC, b24, b25,
      ws + WS_QXI_F, ws + WS_LQC_F,
      ws + WS_QFM, ws + WS_QFC,
      ws + WS_P_XM, ws + WS_P_XC, b31, b32, x,
      out + 2 + 40960, out + 2 + 61440,
      ws + WS_SUMS, (int*)(ws + WS_CNT_FIN), out);
}

// Round 18
// 230.279 us; speedup vs baseline: 1.0981x; 1.0599x over previous
//
#include <hip/hip_runtime.h>
#include <math.h>

#define B5 5
#define DX 4096
#define DT 4096
#define DR 4097   // T + D

// ---------------- workspace layout (floats) ----------------
enum {
  WS_SUMS  = 0,                    // [kld1, kld2, nll]
  WS_CNT_XI  = 3,
  WS_CNT_FIN = 4,
  WS_CNT_ARD = 5,
  WS_ZERO_END = 8,
  WS_ACT1  = 16,                   // relu(h1+b1)   (20480)
  WS_ACT23 = WS_ACT1  + 20480,
  WS_ACT3  = WS_ACT23 + 20480,
  WS_QXI_F = WS_ACT3  + 20480,
  WS_LQC_F = WS_QXI_F + 20480,
  WS_XIV   = WS_LQC_F + 20480,
  WS_Z     = WS_XIV   + 20480,
  WS_KSS   = WS_Z     + 20480,     // 25 (pad 32)
  WS_KXS   = WS_KSS + 32,
  WS_F     = WS_KXS + 32,
  WS_QFM   = WS_F   + 8,
  WS_QFC   = WS_QFM + 8,
  WS_PART  = 143472,               // 16-aligned
  // partials [ks][b][dout], NS=64 (H23: 128)
  WS_P_H1  = WS_PART,
  WS_P_QXI = WS_P_H1  + 1310720,
  WS_P_LQC = WS_P_QXI + 1310720,
  WS_P_ZM  = WS_P_LQC + 1310720,
  WS_P_ZC  = WS_P_ZM  + 1310720,
  WS_P_H23 = WS_P_ZC  + 1310720,   // 128*5*4096
  WS_P_H3  = WS_P_H23 + 2621440,
  WS_P_RM  = WS_P_H3  + 1310720,   // 64*5*4097
  WS_P_RC  = WS_P_RM  + 1311040,
  WS_P_XM  = WS_P_RC  + 1311040,
  WS_P_XC  = WS_P_XM  + 1310720,
  WS_END   = WS_P_XC  + 1310720    // ~63 MB
};

#define GCOLS 128   // output cols per block
#define GK    64    // k rows per block (NS = din/GK)
#define WROWS 16    // k rows per wave

typedef float f2v __attribute__((ext_vector_type(2)));

__device__ inline float ntl(const float* p) { return __builtin_nontemporal_load(p); }

__device__ inline float wave_sum(float v) {
  #pragma unroll
  for (int o = 32; o > 0; o >>= 1) v += __shfl_down(v, o, 64);
  return v;
}

// ---------------- GEMM body (R15-proven: NT weight loads, plain everything else) ------
// 4 waves/block; wave w owns k-rows [w*16,(w+1)*16): wave-local staging (no
// barrier), 16 nontemporal float2 weight rows, single-barrier LDS combine;
// wave 0 writes the NS=64 split partial (no atomics, no fences).
// PROLOG: 0 raw p0 ; 2 relu(p0[b]*p1[k]+p2[k]) ; 3 concat(x=p0, z=p1)
template<int PROLOG, int DUAL, int ALIGNED>
__device__ __forceinline__ void gemm5_body(
    float* sx, float* red, int bx, int by,
    const float* __restrict__ p0, const float* __restrict__ p1,
    const float* __restrict__ p2,
    const float* __restrict__ Wa, const float* __restrict__ Wb,
    float* __restrict__ Pa,       float* __restrict__ Pb,
    int din, int dout)
{
  const int tid  = threadIdx.x;
  const int lane = tid & 63;
  const int wv   = tid >> 6;
  const long i0  = (long)by * GK;
  const long r0  = i0 + (long)wv * WROWS;

  // wave-local stage: this wave's 5x16 activation tile (no cross-wave dep)
  float* sw = sx + wv * 80;
  for (int t = lane; t < B5 * WROWS; t += 64) {
    int b  = t >> 4;
    int il = t & 15;
    int i  = (int)(r0 + il);
    float v;
    if (PROLOG == 0)      v = p0[(long)b * din + i];
    else if (PROLOG == 2) v = fmaxf(p0[b] * p1[i] + p2[i], 0.f);
    else                  v = (i < DX) ? p0[(long)b * DX + i] : p1[(long)b * DT + (i - DX)];
    sw[t] = v;
  }
  // wave-internal ds_write -> ds_read ordering: no __syncthreads needed

  const long o0 = (long)bx * GCOLS + lane * 2;
  const bool v0 = (o0 < dout);
  const bool v1 = (o0 + 1 < dout);

  float accA[B5][2] = {};
  float accB[B5][2] = {};
  const float* wa = Wa + r0 * dout + o0;
  const float* wb = DUAL ? (Wb + r0 * dout + o0) : nullptr;

  #pragma unroll 8
  for (int il = 0; il < WROWS; ++il) {
    float w0a, w1a, w0b = 0.f, w1b = 0.f;
    if (ALIGNED) {
      f2v ta = __builtin_nontemporal_load((const f2v*)wa);
      w0a = ta.x; w1a = ta.y;
      if (DUAL) {
        f2v tb = __builtin_nontemporal_load((const f2v*)wb);
        w0b = tb.x; w1b = tb.y;
      }
    } else {
      w0a = v0 ? ntl(wa) : 0.f;
      w1a = v1 ? ntl(wa + 1) : 0.f;
      if (DUAL) {
        w0b = v0 ? ntl(wb) : 0.f;
        w1b = v1 ? ntl(wb + 1) : 0.f;
      }
    }
    #pragma unroll
    for (int b = 0; b < B5; ++b) {
      float xv = sw[b * WROWS + il];
      accA[b][0] += xv * w0a; accA[b][1] += xv * w1a;
      if (DUAL) { accB[b][0] += xv * w0b; accB[b][1] += xv * w1b; }
    }
    wa += dout; if (DUAL) wb += dout;
  }

  // single-barrier combine: waves 1..3 dump, wave 0 sums + writes
  const int NJ = DUAL ? 20 : 10;
  if (wv > 0) {
    float* rr = red + (long)(wv - 1) * NJ * 64 + lane;
    #pragma unroll
    for (int b = 0; b < B5; ++b) {
      rr[(b*2)*64] = accA[b][0]; rr[(b*2+1)*64] = accA[b][1];
      if (DUAL) { rr[(10+b*2)*64] = accB[b][0]; rr[(10+b*2+1)*64] = accB[b][1]; }
    }
  }
  __syncthreads();
  if (wv == 0) {
    #pragma unroll
    for (int w2 = 0; w2 < 3; ++w2) {
      const float* rr = red + (long)w2 * NJ * 64 + lane;
      #pragma unroll
      for (int b = 0; b < B5; ++b) {
        accA[b][0] += rr[(b*2)*64]; accA[b][1] += rr[(b*2+1)*64];
        if (DUAL) { accB[b][0] += rr[(10+b*2)*64]; accB[b][1] += rr[(10+b*2+1)*64]; }
      }
    }
    if (v0) {
      #pragma unroll
      for (int b = 0; b < B5; ++b) {
        float* pa = Pa + ((long)by * B5 + b) * dout + o0;
        if (ALIGNED) *(float2*)pa = make_float2(accA[b][0], accA[b][1]);
        else { pa[0] = accA[b][0]; if (v1) pa[1] = accA[b][1]; }
        if (DUAL) {
          float* pb = Pb + ((long)by * B5 + b) * dout + o0;
          if (ALIGNED) *(float2*)pb = make_float2(accB[b][0], accB[b][1]);
          else { pb[0] = accB[b][0]; if (v1) pb[1] = accB[b][1]; }
        }
      }
    }
  }
}

template<int PROLOG, int DUAL, int ALIGNED>
__global__ __launch_bounds__(256) void gemm5(
    const float* __restrict__ p0, const float* __restrict__ p1,
    const float* __restrict__ p2,
    const float* __restrict__ Wa, const float* __restrict__ Wb,
    float* __restrict__ Pa,       float* __restrict__ Pb,
    int din, int dout)
{
  __shared__ float sx[4 * 80];
  __shared__ float red[3 * 20 * 64];
  gemm5_body<PROLOG, DUAL, ALIGNED>(sx, red, blockIdx.x, blockIdx.y,
      p0, p1, p2, Wa, Wb, Pa, Pb, din, dout);
}

// merged G4 (concat(x,z)@W23: 32x128=4096) + G6 (z@W3: 2048)
__global__ __launch_bounds__(256) void gemm5_G46(
    const float* __restrict__ x,   const float* __restrict__ z,
    const float* __restrict__ W23, float* __restrict__ P23,
    const float* __restrict__ W3,  float* __restrict__ P3)
{
  __shared__ float sx[4 * 80];
  __shared__ float red[3 * 20 * 64];
  int id = blockIdx.x;
  if (id < 4096) {
    gemm5_body<3, 0, 1>(sx, red, id & 31, id >> 5, x, z, nullptr,
                        W23, nullptr, P23, nullptr, 8192, 4096);
  } else {
    id -= 4096;
    gemm5_body<0, 0, 1>(sx, red, id & 31, id >> 5, z, nullptr, nullptr,
                        W3, nullptr, P3, nullptr, 4096, 4096);
  }
}

// merged G5 (act23@[W24,W25], dout=4097: 33x64=2112) + G7 (act3@[W31,W32]: 2048)
__global__ __launch_bounds__(256) void gemm5_G57(
    const float* __restrict__ act23,
    const float* __restrict__ W24, const float* __restrict__ W25,
    float* __restrict__ PRM,       float* __restrict__ PRC,
    const float* __restrict__ act3,
    const float* __restrict__ W31, const float* __restrict__ W32,
    float* __restrict__ PXM,       float* __restrict__ PXC)
{
  __shared__ float sx[4 * 80];
  __shared__ float red[3 * 20 * 64];
  int id = blockIdx.x;
  if (id < 2112) {
    gemm5_body<0, 1, 0>(sx, red, id % 33, id / 33, act23, nullptr, nullptr,
                        W24, W25, PRM, PRC, 4096, 4097);
  } else {
    id -= 2112;
    gemm5_body<0, 1, 1>(sx, red, id & 31, id >> 5, act3, nullptr, nullptr,
                        W31, W32, PXM, PXC, 4096, 4096);
  }
}

// ---------------- act reductions (plain partial reads; also zero control floats) ------
__global__ __launch_bounds__(256) void k_act1(
    const float* __restrict__ P, const float* __restrict__ bias, float* __restrict__ act,
    float* __restrict__ ctrl)
{
  if (blockIdx.x == 0 && threadIdx.x < WS_ZERO_END) ctrl[threadIdx.x] = 0.f;
  int idx = blockIdx.x * 256 + threadIdx.x;          // < 20480
  int b = idx >> 12, col = idx & (DT - 1);
  const float* pp = P + (long)b * DT + col;
  float s = 0.f;
  #pragma unroll 8
  for (int ks = 0; ks < 64; ++ks) s += pp[(long)ks * (B5 * DT)];
  act[idx] = fmaxf(s + bias[col], 0.f);
}

__global__ __launch_bounds__(256) void k_act23(
    const float* __restrict__ P23, const float* __restrict__ b23, float* __restrict__ act23,
    const float* __restrict__ P3,  const float* __restrict__ b3,  float* __restrict__ act3)
{
  int idx = blockIdx.x * 256 + threadIdx.x;
  if (idx < B5 * DT) {
    int b = idx >> 12, col = idx & (DT - 1);
    const float* pp = P23 + (long)b * DT + col;
    float s = 0.f;
    #pragma unroll 8
    for (int ks = 0; ks < 128; ++ks) s += pp[(long)ks * (B5 * DT)];
    act23[idx] = fmaxf(s + b23[col], 0.f);
  } else {
    int j = idx - B5 * DT;
    int b = j >> 12, col = j & (DT - 1);
    const float* pp = P3 + (long)b * DT + col;
    float s = 0.f;
    #pragma unroll 8
    for (int ks = 0; ks < 64; ++ks) s += pp[(long)ks * (B5 * DT)];
    act3[j] = fmaxf(s + b3[col], 0.f);
  }
}

// ---------------- k_xi: reduce qxi/lqc partials, finalize, sample xi ----------------
__global__ __launch_bounds__(256) void k_xi(
    const float* __restrict__ Pq, const float* __restrict__ Pl,
    const float* __restrict__ b11, const float* __restrict__ b12,
    const float* __restrict__ eps_xi,
    float* __restrict__ qf, float* __restrict__ lf, float* __restrict__ xiv)
{
  int idx = blockIdx.x * 256 + threadIdx.x;
  if (idx >= B5 * DT) return;
  int b = idx >> 12, col = idx & (DT - 1);
  const float* pq = Pq + (long)b * DT + col;
  const float* pl = Pl + (long)b * DT + col;
  float sq = 0.f, sl = 0.f;
  #pragma unroll 8
  for (int ks = 0; ks < 64; ++ks) { sq += pq[(long)ks * (B5 * DT)]; sl += pl[(long)ks * (B5 * DT)]; }
  float qm = sq + b11[col];
  float lq = sl + b12[col];
  qf[idx] = qm; lf[idx] = lq;
  xiv[idx] = expf(0.5f * lq) * eps_xi[idx] + qm;
}

// ---------------- ARD + last-block GP solve ----------------
__global__ __launch_bounds__(256) void k_ardgp(
    const float* __restrict__ s,    const float* __restrict__ xiv,
    const float* __restrict__ w,    const float* __restrict__ sigma,
    const float* __restrict__ t_in, const float* __restrict__ eps_f,
    float* __restrict__ Kss, float* __restrict__ Kxs, int* __restrict__ cnt,
    float* __restrict__ fv, float* __restrict__ qfm, float* __restrict__ qfc)
{
  const int bid = blockIdx.x;
  const bool xs = (bid >= 25);
  int q = xs ? bid - 25 : bid;
  const int i = q / 5, j = q % 5;
  const float* aa = xs ? (xiv + (long)i * DT) : (s + (long)i * DT);
  const float* bb = s + (long)j * DT;

  float sum = 0.f;
  for (int t = threadIdx.x; t < DT; t += 256) {
    float d = aa[t] - bb[t];
    sum += w[t] * d * d;
  }
  sum = wave_sum(sum);
  __shared__ float red[4];
  int lane = threadIdx.x & 63, wv = threadIdx.x >> 6;
  if (lane == 0) red[wv] = sum;
  __syncthreads();

  if (threadIdx.x == 0) {
    float tot = red[0] + red[1] + red[2] + red[3];
    float sg = sigma[0];
    float K = sg * sg * expf(-0.5f * tot);
    (xs ? Kxs : Kss)[i * 5 + j] = K;
    __threadfence();
    int old = atomicAdd(cnt, 1);
    if (old == 49) {
      __threadfence();
      double M[5][5], Inv[5][5];
      for (int a = 0; a < 5; ++a)
        for (int b = 0; b < 5; ++b) { M[a][b] = Kss[a * 5 + b]; Inv[a][b] = (a == b) ? 1.0 : 0.0; }
      for (int c = 0; c < 5; ++c) {
        int p = c; double best = fabs(M[c][c]);
        for (int r = c + 1; r < 5; ++r) if (fabs(M[r][c]) > best) { best = fabs(M[r][c]); p = r; }
        if (p != c)
          for (int k = 0; k < 5; ++k) {
            double tm = M[c][k]; M[c][k] = M[p][k]; M[p][k] = tm;
            tm = Inv[c][k]; Inv[c][k] = Inv[p][k]; Inv[p][k] = tm;
          }
        double piv = 1.0 / M[c][c];
        for (int k = 0; k < 5; ++k) { M[c][k] *= piv; Inv[c][k] *= piv; }
        for (int r = 0; r < 5; ++r) if (r != c) {
          double m = M[r][c];
          for (int k = 0; k < 5; ++k) { M[r][k] -= m * M[c][k]; Inv[r][k] -= m * Inv[c][k]; }
        }
      }
      double kk[5][5];
      for (int a = 0; a < 5; ++a)
        for (int b = 0; b < 5; ++b) {
          double acc = 0.0;
          for (int k = 0; k < 5; ++k) acc += (double)Kxs[a * 5 + k] * Inv[k][b];
          kk[a][b] = acc;
        }
      double sg2 = (double)sg * (double)sg;
      for (int a = 0; a < 5; ++a) {
        double qm = 0.0, qc = sg2;
        for (int b = 0; b < 5; ++b) { qm += kk[a][b] * (double)t_in[b]; qc -= kk[a][b] * (double)Kxs[a * 5 + b]; }
        if (qc < 1e-12) qc = 1e-12;
        qfm[a] = (float)qm;
        qfc[a] = (float)qc;
        fv[a]  = sqrtf((float)qc) * eps_f[a] + (float)qm;
      }
    }
  }
}

// ---------------- k_z ----------------
__global__ __launch_bounds__(256) void k_z(
    const float* __restrict__ Pm, const float* __restrict__ Pc,
    const float* __restrict__ b21, const float* __restrict__ b22,
    const float* __restrict__ eps_z,
    float* __restrict__ out_zm, float* __restrict__ out_zc,
    float* __restrict__ zv, float* __restrict__ kld1sum)
{
  int idx = blockIdx.x * 256 + threadIdx.x;
  float term = 0.f;
  if (idx < B5 * DT) {
    int b = idx >> 12, col = idx & (DT - 1);
    const float* pm = Pm + (long)b * DT + col;
    const float* pc = Pc + (long)b * DT + col;
    float sm = 0.f, sc = 0.f;
    #pragma unroll 8
    for (int ks = 0; ks < 64; ++ks) { sm += pm[(long)ks * (B5 * DT)]; sc += pc[(long)ks * (B5 * DT)]; }
    float zm = sm + b21[col];
    float zc = sc + b22[col];
    out_zm[idx] = zm; out_zc[idx] = zc;
    zv[idx] = expf(0.5f * zc) * eps_z[idx] + zm;
    term = -zc - 1.f + expf(zc) + zm * zm;
  }
  term = wave_sum(term);
  if ((threadIdx.x & 63) == 0) atomicAdd(kld1sum, term);
}

// ---------------- FIN ----------------
__global__ __launch_bounds__(256) void k_fin(
    const float* __restrict__ Prm, const float* __restrict__ Prc,
    const float* __restrict__ b24, const float* __restrict__ b25,
    const float* __restrict__ qxi, const float* __restrict__ lqc,
    const float* __restrict__ qfm, const float* __restrict__ qfc,
    const float* __restrict__ Pxm, const float* __restrict__ Pxc,
    const float* __restrict__ b31, const float* __restrict__ b32,
    const float* __restrict__ x,
    float* __restrict__ out_xm, float* __restrict__ out_xc,
    float* __restrict__ sums, int* __restrict__ cnt, float* __restrict__ out01)
{
  const int gtid = blockIdx.x * 256 + threadIdx.x;
  float t2 = 0.f, t3 = 0.f;
  if (gtid < B5 * DR) {
    int b = gtid / DR, col = gtid % DR;
    const float* pm = Prm + (long)b * DR + col;
    const float* pc = Prc + (long)b * DR + col;
    float sm = 0.f, sc = 0.f;
    #pragma unroll 8
    for (int ks = 0; ks < 64; ++ks) { sm += pm[(long)ks * (B5 * DR)]; sc += pc[(long)ks * (B5 * DR)]; }
    float rm = sm + b24[col];
    float rc = sc + b25[col];
    float qm, qc;
    if (col < DT) { qm = qxi[(long)b * DT + col]; qc = lqc[(long)b * DT + col]; }
    else          { qm = qfm[b]; qc = logf(qfc[b]); }
    float d = qm - rm;
    t2 = rc - qc - 1.f + expf(qc - rc) + d * d * expf(-rc);
  } else {
    int idx = gtid - B5 * DR;
    if (idx < B5 * DX) {
      int b = idx >> 12, col = idx & (DX - 1);
      const float* pm = Pxm + (long)b * DX + col;
      const float* pc = Pxc + (long)b * DX + col;
      float sm = 0.f, sc = 0.f;
      #pragma unroll 8
      for (int ks = 0; ks < 64; ++ks) { sm += pm[(long)ks * (B5 * DX)]; sc += pc[(long)ks * (B5 * DX)]; }
      float xm = sm + b31[col];
      float xc = sc + b32[col];
      out_xm[idx] = xm; out_xc[idx] = xc;
      float d = x[idx] - xm;
      t3 = 1.14472988584940017f + xc + expf(-xc) * d * d;  // ln(pi) + ...
    }
  }
  t2 = wave_sum(t2);
  t3 = wave_sum(t3);
  if ((threadIdx.x & 63) == 0) {
    if (t2 != 0.f) atomicAdd(&sums[1], t2);
    if (t3 != 0.f) atomicAdd(&sums[2], t3);
  }
  __syncthreads();
  if (threadIdx.x == 0) {
    __threadfence();
    int old = atomicAdd(cnt, 1);
    if (old == (int)gridDim.x - 1) {
      __threadfence();
      out01[0] = 0.5f * (sums[0] + sums[1]) / (float)B5;
      out01[1] = 0.5f * sums[2] / (float)B5;
    }
  }
}

// ---------------- launch ----------------
extern "C" void kernel_launch(void* const* d_in, const int* in_sizes, int n_in,
                              void* d_out, int out_size, void* d_ws, size_t ws_size,
                              hipStream_t stream)
{
  const float* x      = (const float*)d_in[0];
  const float* eps_xi = (const float*)d_in[1];
  const float* eps_f  = (const float*)d_in[2];
  const float* eps_z  = (const float*)d_in[3];
  const float* W1  = (const float*)d_in[4];  const float* b1  = (const float*)d_in[5];
  const float* W11 = (const float*)d_in[6];  const float* b11 = (const float*)d_in[7];
  const float* W12 = (const float*)d_in[8];  const float* b12 = (const float*)d_in[9];
  const float* W2  = (const float*)d_in[10]; const float* b2  = (const float*)d_in[11];
  const float* W21 = (const float*)d_in[12]; const float* b21 = (const float*)d_in[13];
  const float* W22 = (const float*)d_in[14]; const float* b22 = (const float*)d_in[15];
  const float* W23 = (const float*)d_in[16]; const float* b23 = (const float*)d_in[17];
  const float* W24 = (const float*)d_in[18]; const float* b24 = (const float*)d_in[19];
  const float* W25 = (const float*)d_in[20]; const float* b25 = (const float*)d_in[21];
  const float* W3  = (const float*)d_in[22]; const float* b3  = (const float*)d_in[23];
  const float* W31 = (const float*)d_in[24]; const float* b31 = (const float*)d_in[25];
  const float* W32 = (const float*)d_in[26]; const float* b32 = (const float*)d_in[27];
  const float* s     = (const float*)d_in[28];
  const float* t     = (const float*)d_in[29];
  const float* sigma = (const float*)d_in[30];
  const float* w     = (const float*)d_in[31];

  float* ws  = (float*)d_ws;
  float* out = (float*)d_out;

  dim3 blk(256);

  // G1: h1 partials = x @ W1                    (2048 blocks)
  gemm5<0,0,1><<<dim3(32,64), blk, 0, stream>>>(
      x, nullptr, nullptr, W1, nullptr, ws + WS_P_H1, nullptr, 4096, 4096);
  // act1 = relu(sum P_H1 + b1)  (+ zero control floats)
  k_act1<<<80, blk, 0, stream>>>(ws + WS_P_H1, b1, ws + WS_ACT1, ws);
  // G2: qxi/lqc partials = act1 @ [W11, W12]
  gemm5<0,1,1><<<dim3(32,64), blk, 0, stream>>>(
      ws + WS_ACT1, nullptr, nullptr, W11, W12, ws + WS_P_QXI, ws + WS_P_LQC, 4096, 4096);
  // k_xi: finalize qxi/lqc + sample xi
  k_xi<<<80, blk, 0, stream>>>(
      ws + WS_P_QXI, ws + WS_P_LQC, b11, b12, eps_xi,
      ws + WS_QXI_F, ws + WS_LQC_F, ws + WS_XIV);
  // ARD + GP solve
  k_ardgp<<<50, blk, 0, stream>>>(
      s, ws + WS_XIV, w, sigma, t, eps_f,
      ws + WS_KSS, ws + WS_KXS, (int*)(ws + WS_CNT_ARD),
      ws + WS_F, ws + WS_QFM, ws + WS_QFC);
  // G3: zm/zc partials = relu(f*W2+b2) @ [W21, W22]
  gemm5<2,1,1><<<dim3(32,64), blk, 0, stream>>>(
      ws + WS_F, W2, b2, W21, W22, ws + WS_P_ZM, ws + WS_P_ZC, 4096, 4096);
  // k_z: finalize zm/zc + sample z + kld1
  k_z<<<80, blk, 0, stream>>>(
      ws + WS_P_ZM, ws + WS_P_ZC, b21, b22, eps_z,
      out + 2, out + 2 + 20480, ws + WS_Z, ws + WS_SUMS);
  // G4+G6: h23 partials ; h3 partials          (6144 blocks)
  gemm5_G46<<<6144, blk, 0, stream>>>(
      x, ws + WS_Z, W23, ws + WS_P_H23, W3, ws + WS_P_H3);
  // act23 / act3
  k_act23<<<160, blk, 0, stream>>>(
      ws + WS_P_H23, b23, ws + WS_ACT23, ws + WS_P_H3, b3, ws + WS_ACT3);
  // G5+G7: rm/rc partials ; xm/xc partials     (4160 blocks)
  gemm5_G57<<<4160, blk, 0, stream>>>(
      ws + WS_ACT23, W24, W25, ws + WS_P_RM, ws + WS_P_RC,
      ws + WS_ACT3,  W31, W32, ws + WS_P_XM, ws + WS_P_XC);
  // FIN
  k_fin<<<161, blk, 0, stream>>>(
      ws + WS_P_RM, ws + WS_P_RC, b24, b25,
      ws + WS_QXI_F, ws + WS_LQC_F,
      ws + WS_QFM, ws + WS_QFC,
      ws + WS_P_XM, ws + WS_P_XC, b31, b32, x,
      out + 2 + 40960, out + 2 + 61440,
      ws + WS_SUMS, (int*)(ws + WS_CNT_FIN), out);
}